// Round 1
// baseline (2501.724 us; speedup 1.0000x reference)
//
#include <hip/hip_runtime.h>

#define N_NODES 50000
#define N_EDGES 800000
#define E_TOT   (N_EDGES + N_NODES)   // self-loops appended
#define HEADS   4
#define HIDDEN  64
#define F1      128                   // IN_DIM
#define F2      256                   // HEADS*HIDDEN
#define EPS     1e-5f
#define SLOPE   0.2f

// ---- order-preserving float<->uint key for atomicMax on floats ----
__device__ __forceinline__ unsigned fkey(float f) {
    unsigned u = __float_as_uint(f);
    return (u & 0x80000000u) ? ~u : (u | 0x80000000u);
}
__device__ __forceinline__ float unkey(unsigned k) {
    return __uint_as_float((k & 0x80000000u) ? (k & 0x7fffffffu) : ~k);
}

// ---- column sums / sums-of-squares for training-mode BatchNorm ----
template<int C>
__global__ void bn_stats(const float* __restrict__ X,
                         float* __restrict__ sums, float* __restrict__ sumsq) {
    int t = threadIdx.x;            // blockDim.x == C
    float s = 0.f, q = 0.f;
    for (int r = blockIdx.x; r < N_NODES; r += gridDim.x) {
        float v = X[(size_t)r * C + t];
        s += v; q += v * v;
    }
    atomicAdd(&sums[t], s);
    atomicAdd(&sumsq[t], q);
}

// ---- fused BN(+ReLU) -> GEMM (row @ W, K->256) -> attention dots ----
// One block of 256 threads per node row. Thread t = h*64+c owns hl[n,h,c].
template<int K, bool RELU>
__global__ __launch_bounds__(256)
void gemm_att(const float* __restrict__ X,
              const float* __restrict__ sums, const float* __restrict__ sumsq,
              const float* __restrict__ gamma, const float* __restrict__ beta,
              const float* __restrict__ W,
              const float* __restrict__ att_s, const float* __restrict__ att_d,
              float* __restrict__ hl, float* __restrict__ a_src, float* __restrict__ a_dst) {
    int n = blockIdx.x, t = threadIdx.x;
    __shared__ float sh[K];
    const float invN = 1.f / (float)N_NODES;
    for (int k = t; k < K; k += 256) {
        float m  = sums[k] * invN;
        float vv = sumsq[k] * invN - m * m;
        float y  = (X[(size_t)n * K + k] - m) * rsqrtf(vv + EPS) * gamma[k] + beta[k];
        if (RELU) y = fmaxf(y, 0.f);
        sh[k] = y;
    }
    __syncthreads();
    float acc = 0.f;
#pragma unroll 8
    for (int k = 0; k < K; k++) acc = fmaf(sh[k], W[k * F2 + t], acc);
    hl[(size_t)n * F2 + t] = acc;

    float vs = acc * att_s[t];
    float vd = acc * att_d[t];
#pragma unroll
    for (int o = 32; o > 0; o >>= 1) { vs += __shfl_xor(vs, o); vd += __shfl_xor(vd, o); }
    if ((t & 63) == 0) { int h = t >> 6; a_src[n * 4 + h] = vs; a_dst[n * 4 + h] = vd; }
}

// ---- edge pass 1: segment max of leaky_relu(a_src[s]+a_dst[d]) per (dst, head) ----
__global__ void edge_max(const int* __restrict__ esrc, const int* __restrict__ edst,
                         const float* __restrict__ a_src, const float* __restrict__ a_dst,
                         unsigned* __restrict__ emax) {
    long long i = (long long)blockIdx.x * blockDim.x + threadIdx.x;
    if (i >= (long long)E_TOT * HEADS) return;
    int e = (int)(i >> 2), h = (int)(i & 3);
    int s = e < N_EDGES ? esrc[e] : (e - N_EDGES);
    int d = e < N_EDGES ? edst[e] : (e - N_EDGES);
    float v = a_src[s * 4 + h] + a_dst[d * 4 + h];
    v = v > 0.f ? v : SLOPE * v;
    atomicMax(&emax[d * 4 + h], fkey(v));
}

// ---- edge pass 2: softmax denominator ----
__global__ void edge_denom(const int* __restrict__ esrc, const int* __restrict__ edst,
                           const float* __restrict__ a_src, const float* __restrict__ a_dst,
                           const unsigned* __restrict__ emax, float* __restrict__ denom) {
    long long i = (long long)blockIdx.x * blockDim.x + threadIdx.x;
    if (i >= (long long)E_TOT * HEADS) return;
    int e = (int)(i >> 2), h = (int)(i & 3);
    int s = e < N_EDGES ? esrc[e] : (e - N_EDGES);
    int d = e < N_EDGES ? edst[e] : (e - N_EDGES);
    float v = a_src[s * 4 + h] + a_dst[d * 4 + h];
    v = v > 0.f ? v : SLOPE * v;
    atomicAdd(&denom[d * 4 + h], expf(v - unkey(emax[d * 4 + h])));
}

// ---- edge pass 3: alpha * hl[src] scattered to dst (atomicAdd) ----
// MEAN=false: out[d, h*64+c] (concat).  MEAN=true: out[d, c] += 0.25*msg (head mean).
template<bool MEAN>
__global__ __launch_bounds__(256)
void edge_aggr(const int* __restrict__ esrc, const int* __restrict__ edst,
               const float* __restrict__ a_src, const float* __restrict__ a_dst,
               const unsigned* __restrict__ emax, const float* __restrict__ denom,
               const float* __restrict__ hl, float* __restrict__ out) {
    int e = blockIdx.x, t = threadIdx.x;
    int s = e < N_EDGES ? esrc[e] : (e - N_EDGES);
    int d = e < N_EDGES ? edst[e] : (e - N_EDGES);
    int h = t >> 6;
    float v = a_src[s * 4 + h] + a_dst[d * 4 + h];
    v = v > 0.f ? v : SLOPE * v;
    float alpha = expf(v - unkey(emax[d * 4 + h])) / denom[d * 4 + h];
    float msg = alpha * hl[(size_t)s * F2 + t];
    if (MEAN) atomicAdd(&out[(size_t)d * 64 + (t & 63)], 0.25f * msg);
    else      atomicAdd(&out[(size_t)d * F2 + t], msg);
}

__global__ void add_bias(float* __restrict__ out, const float* __restrict__ bias) {
    size_t i = (size_t)blockIdx.x * blockDim.x + threadIdx.x;
    if (i < (size_t)N_NODES * 64) out[i] += bias[i & 63];
}

extern "C" void kernel_launch(void* const* d_in, const int* in_sizes, int n_in,
                              void* d_out, int out_size, void* d_ws, size_t ws_size,
                              hipStream_t stream) {
    const float* x        = (const float*)d_in[0];
    const int*   edge     = (const int*)  d_in[1];   // [2, E] flat: row0=src, row1=dst
    const float* gamma1   = (const float*)d_in[2];
    const float* beta1    = (const float*)d_in[3];
    const float* W1       = (const float*)d_in[4];
    const float* att_src1 = (const float*)d_in[5];
    const float* att_dst1 = (const float*)d_in[6];
    // d_in[7] = bias1: dead (absorbed by BatchNorm2's mean subtraction)
    const float* gamma2   = (const float*)d_in[8];
    const float* beta2    = (const float*)d_in[9];
    const float* W2       = (const float*)d_in[10];
    const float* att_src2 = (const float*)d_in[11];
    const float* att_dst2 = (const float*)d_in[12];
    const float* bias2    = (const float*)d_in[13];
    float* out = (float*)d_out;

    const int* esrc = edge;
    const int* edst = edge + N_EDGES;

    // ---- workspace layout (floats) ----
    float* wsf = (float*)d_ws;
    size_t o = 0;
    float*    hl     = wsf + o; o += (size_t)N_NODES * F2;   // reused by both layers
    float*    acc1   = wsf + o; o += (size_t)N_NODES * F2;   // GAT1 output (needs zero)
    size_t zstart = o;                                        // ---- zeroed block ----
    unsigned* emax1  = (unsigned*)(wsf + o); o += N_NODES * 4;
    float*    denom1 = wsf + o; o += N_NODES * 4;
    unsigned* emax2  = (unsigned*)(wsf + o); o += N_NODES * 4;
    float*    denom2 = wsf + o; o += N_NODES * 4;
    float*    sums1  = wsf + o; o += F1;
    float*    sumsq1 = wsf + o; o += F1;
    float*    sums2  = wsf + o; o += F2;
    float*    sumsq2 = wsf + o; o += F2;
    size_t zbytes = (o - zstart) * sizeof(float);             // ---- end zeroed ----
    float*    a_src1 = wsf + o; o += N_NODES * 4;
    float*    a_dst1 = wsf + o; o += N_NODES * 4;
    float*    a_src2 = wsf + o; o += N_NODES * 4;
    float*    a_dst2 = wsf + o; o += N_NODES * 4;

    hipMemsetAsync(acc1, 0, (size_t)N_NODES * F2 * sizeof(float), stream);
    hipMemsetAsync(wsf + zstart, 0, zbytes, stream);
    hipMemsetAsync(out, 0, (size_t)N_NODES * 64 * sizeof(float), stream);

    const int eg = (int)(((long long)E_TOT * HEADS + 255) / 256);

    // ---- Layer 1: BN1 (folded) -> GEMM+att -> softmax -> aggregate ----
    bn_stats<F1><<<512, F1, 0, stream>>>(x, sums1, sumsq1);
    gemm_att<F1, false><<<N_NODES, 256, 0, stream>>>(x, sums1, sumsq1, gamma1, beta1,
                                                     W1, att_src1, att_dst1,
                                                     hl, a_src1, a_dst1);
    edge_max  <<<eg, 256, 0, stream>>>(esrc, edst, a_src1, a_dst1, emax1);
    edge_denom<<<eg, 256, 0, stream>>>(esrc, edst, a_src1, a_dst1, emax1, denom1);
    edge_aggr<false><<<E_TOT, 256, 0, stream>>>(esrc, edst, a_src1, a_dst1,
                                                emax1, denom1, hl, acc1);

    // ---- Layer 2: BN2+ReLU (folded) -> GEMM+att -> softmax -> head-mean aggregate ----
    bn_stats<F2><<<512, F2, 0, stream>>>(acc1, sums2, sumsq2);
    gemm_att<F2, true><<<N_NODES, 256, 0, stream>>>(acc1, sums2, sumsq2, gamma2, beta2,
                                                    W2, att_src2, att_dst2,
                                                    hl, a_src2, a_dst2);
    edge_max  <<<eg, 256, 0, stream>>>(esrc, edst, a_src2, a_dst2, emax2);
    edge_denom<<<eg, 256, 0, stream>>>(esrc, edst, a_src2, a_dst2, emax2, denom2);
    edge_aggr<true><<<E_TOT, 256, 0, stream>>>(esrc, edst, a_src2, a_dst2,
                                               emax2, denom2, hl, out);

    add_bias<<<(N_NODES * 64 + 255) / 256, 256, 0, stream>>>(out, bias2);
}

// Round 2
// 831.187 us; speedup vs baseline: 3.0098x; 3.0098x over previous
//
#include <hip/hip_runtime.h>

#define N_NODES 50000
#define N_EDGES 800000
#define E_TOT   (N_EDGES + N_NODES)   // self-loops appended
#define HEADS   4
#define F1      128                   // IN_DIM
#define F2      256                   // HEADS*HIDDEN
#define EPS     1e-5f
#define SLOPE   0.2f
#define CAP     448                   // max in-LDS degree (max observed deg ~ Poisson(16) tail << 448)
#define ROWS    16                    // rows per gemm block (50000 = 16*3125)

// ---- column sums / sums-of-squares for training-mode BatchNorm ----
template<int C>
__global__ void bn_stats(const float* __restrict__ X,
                         float* __restrict__ sums, float* __restrict__ sumsq) {
    int t = threadIdx.x;            // blockDim.x == C
    float s = 0.f, q = 0.f;
    for (int r = blockIdx.x; r < N_NODES; r += gridDim.x) {
        float v = X[(size_t)r * C + t];
        s += v; q += v * v;
    }
    atomicAdd(&sums[t], s);
    atomicAdd(&sumsq[t], q);
}

// ---- CSR build: degree histogram (init 1 for self-loop), scan, scatter ----
__global__ void deg_init(int* __restrict__ deg) {
    int i = blockIdx.x * 256 + threadIdx.x;
    if (i < N_NODES) deg[i] = 1;
}

__global__ void deg_count(const int* __restrict__ edst, int* __restrict__ deg) {
    int i = blockIdx.x * 256 + threadIdx.x;
    if (i < N_EDGES) atomicAdd(&deg[edst[i]], 1);
}

__global__ __launch_bounds__(1024)
void scan_rowptr(const int* __restrict__ deg, int* __restrict__ rowptr,
                 int* __restrict__ cursor) {
    __shared__ int sdata[1024];
    __shared__ int carry;
    int t = threadIdx.x;
    if (t == 0) { carry = 0; rowptr[0] = 0; }
    __syncthreads();
    for (int base = 0; base < N_NODES; base += 1024) {
        int i = base + t;
        int v = (i < N_NODES) ? deg[i] : 0;
        sdata[t] = v;
        __syncthreads();
        for (int off = 1; off < 1024; off <<= 1) {
            int x = (t >= off) ? sdata[t - off] : 0;
            __syncthreads();
            sdata[t] += x;
            __syncthreads();
        }
        int incl = sdata[t];
        int c = carry;
        __syncthreads();
        if (t == 1023) carry = c + incl;
        if (i < N_NODES) { rowptr[i + 1] = c + incl; cursor[i] = c + incl - v; }
        __syncthreads();
    }
}

__global__ void fill_csr(const int* __restrict__ esrc, const int* __restrict__ edst,
                         int* __restrict__ cursor, int* __restrict__ col) {
    int i = blockIdx.x * 256 + threadIdx.x;
    if (i < N_EDGES) {
        int d = edst[i];
        int p = atomicAdd(&cursor[d], 1);
        col[p] = esrc[i];
    } else if (i < E_TOT) {
        int n = i - N_EDGES;             // self loop
        int p = atomicAdd(&cursor[n], 1);
        col[p] = n;
    }
}

// ---- fused BN(+ReLU) -> GEMM (16 rows @ W) -> attention dots ----
template<int K, bool RELU>
__global__ __launch_bounds__(256)
void gemm_att(const float* __restrict__ X,
              const float* __restrict__ sums, const float* __restrict__ sumsq,
              const float* __restrict__ gamma, const float* __restrict__ beta,
              const float* __restrict__ W,
              const float* __restrict__ att_s, const float* __restrict__ att_d,
              float* __restrict__ hl, float* __restrict__ a_src, float* __restrict__ a_dst) {
    int n0 = blockIdx.x * ROWS, t = threadIdx.x;
    __shared__ float sh[ROWS * K];
    const float invN = 1.f / (float)N_NODES;
    for (int idx = t; idx < ROWS * K; idx += 256) {
        int k = idx & (K - 1), r = idx / K;
        float m  = sums[k] * invN;
        float vv = sumsq[k] * invN - m * m;
        float y  = (X[(size_t)(n0 + r) * K + k] - m) * rsqrtf(vv + EPS) * gamma[k] + beta[k];
        if (RELU) y = fmaxf(y, 0.f);
        sh[idx] = y;
    }
    __syncthreads();
    float acc[ROWS];
#pragma unroll
    for (int r = 0; r < ROWS; r++) acc[r] = 0.f;
    for (int k = 0; k < K; k += 4) {
        float w0 = W[(size_t)(k + 0) * F2 + t];
        float w1 = W[(size_t)(k + 1) * F2 + t];
        float w2 = W[(size_t)(k + 2) * F2 + t];
        float w3 = W[(size_t)(k + 3) * F2 + t];
#pragma unroll
        for (int r = 0; r < ROWS; r++) {
            float4 xv = *(const float4*)&sh[r * K + k];
            acc[r] = fmaf(xv.x, w0, acc[r]);
            acc[r] = fmaf(xv.y, w1, acc[r]);
            acc[r] = fmaf(xv.z, w2, acc[r]);
            acc[r] = fmaf(xv.w, w3, acc[r]);
        }
    }
    float as = att_s[t], ad = att_d[t];
    int h = t >> 6;
#pragma unroll
    for (int r = 0; r < ROWS; r++) {
        hl[(size_t)(n0 + r) * F2 + t] = acc[r];
        float vs = acc[r] * as, vd = acc[r] * ad;
#pragma unroll
        for (int o = 32; o > 0; o >>= 1) { vs += __shfl_xor(vs, o); vd += __shfl_xor(vd, o); }
        if ((t & 63) == 0) { a_src[(n0 + r) * 4 + h] = vs; a_dst[(n0 + r) * 4 + h] = vd; }
    }
}

// ---- per-dst-node softmax + aggregation, no atomics ----
// One 256-thread block per destination node. Softmax without max-subtraction
// (exactly equal: exp(v-max)/sum exp(v-max) == exp(v)/sum exp(v); |v| is O(3)).
template<bool MEAN>
__global__ __launch_bounds__(256)
void node_aggr(const int* __restrict__ rowptr, const int* __restrict__ col,
               const float* __restrict__ a_src, const float* __restrict__ a_dst,
               const float* __restrict__ hl, const float* __restrict__ bias,
               float* __restrict__ out) {
    int n = blockIdx.x, t = threadIdx.x;
    int start = rowptr[n];
    int deg = rowptr[n + 1] - start;
    __shared__ float se[CAP * 4];
    __shared__ int   scol[CAP];
    __shared__ float wred[16];
    __shared__ float sdenom[4];
    __shared__ float sred[256];
    int h4 = t & 3;
    float adn = a_dst[n * 4 + h4];
    float local = 0.f;
    bool fits = (deg <= CAP);
    if (fits) {
        for (int i = t; i < deg; i += 256) scol[i] = col[start + i];
        __syncthreads();
        for (int p = t; p < deg * 4; p += 256) {   // p&3 == t&3 == h4
            int i = p >> 2;
            float v = a_src[scol[i] * 4 + h4] + adn;
            v = v > 0.f ? v : SLOPE * v;
            float e = __expf(v);
            se[p] = e;
            local += e;
        }
    } else {
        for (int p = t; p < deg * 4; p += 256) {
            int i = p >> 2;
            float v = a_src[col[start + i] * 4 + h4] + adn;
            v = v > 0.f ? v : SLOPE * v;
            local += __expf(v);
        }
    }
    // reduce over the 16 lanes/wave sharing h4, then across 4 waves
#pragma unroll
    for (int off = 4; off < 64; off <<= 1) local += __shfl_xor(local, off);
    int lane = t & 63, w = t >> 6;
    if (lane < 4) wred[w * 4 + lane] = local;
    __syncthreads();
    if (t < 4) sdenom[t] = wred[t] + wred[4 + t] + wred[8 + t] + wred[12 + t];
    __syncthreads();

    int h = t >> 6;
    float rden = 1.f / sdenom[h];
    float acc = 0.f;
    if (fits) {
#pragma unroll 4
        for (int i = 0; i < deg; i++) {
            float alpha = se[i * 4 + h] * rden;
            acc = fmaf(alpha, hl[(size_t)scol[i] * F2 + t], acc);
        }
    } else {
        float adh = a_dst[n * 4 + h];
        for (int i = 0; i < deg; i++) {
            int s = col[start + i];
            float v = a_src[s * 4 + h] + adh;
            v = v > 0.f ? v : SLOPE * v;
            acc = fmaf(__expf(v) * rden, hl[(size_t)s * F2 + t], acc);
        }
    }
    if (MEAN) {
        sred[t] = acc;
        __syncthreads();
        if (t < 64) {
            float s = sred[t] + sred[t + 64] + sred[t + 128] + sred[t + 192];
            out[(size_t)n * 64 + t] = 0.25f * s + bias[t];
        }
    } else {
        out[(size_t)n * F2 + t] = acc;
    }
}

extern "C" void kernel_launch(void* const* d_in, const int* in_sizes, int n_in,
                              void* d_out, int out_size, void* d_ws, size_t ws_size,
                              hipStream_t stream) {
    const float* x        = (const float*)d_in[0];
    const int*   edge     = (const int*)  d_in[1];   // [2, E]: row0=src, row1=dst
    const float* gamma1   = (const float*)d_in[2];
    const float* beta1    = (const float*)d_in[3];
    const float* W1       = (const float*)d_in[4];
    const float* att_src1 = (const float*)d_in[5];
    const float* att_dst1 = (const float*)d_in[6];
    // d_in[7] = bias1: dead (absorbed by BatchNorm2's mean subtraction)
    const float* gamma2   = (const float*)d_in[8];
    const float* beta2    = (const float*)d_in[9];
    const float* W2       = (const float*)d_in[10];
    const float* att_src2 = (const float*)d_in[11];
    const float* att_dst2 = (const float*)d_in[12];
    const float* bias2    = (const float*)d_in[13];
    float* out = (float*)d_out;

    const int* esrc = edge;
    const int* edst = edge + N_EDGES;

    // ---- workspace layout ----
    float* wsf = (float*)d_ws;
    size_t o = 0;
    float* hl     = wsf + o; o += (size_t)N_NODES * F2;   // reused by both layers
    float* acc1   = wsf + o; o += (size_t)N_NODES * F2;   // GAT1 output (fully overwritten)
    float* a_src1 = wsf + o; o += N_NODES * 4;
    float* a_dst1 = wsf + o; o += N_NODES * 4;
    float* a_src2 = wsf + o; o += N_NODES * 4;
    float* a_dst2 = wsf + o; o += N_NODES * 4;
    size_t zstart = o;                                     // ---- zeroed block ----
    float* sums1  = wsf + o; o += F1;
    float* sumsq1 = wsf + o; o += F1;
    float* sums2  = wsf + o; o += F2;
    float* sumsq2 = wsf + o; o += F2;
    size_t zbytes = (o - zstart) * sizeof(float);          // ---- end zeroed ----
    int* deg    = (int*)(wsf + o); o += N_NODES;
    int* rowptr = (int*)(wsf + o); o += N_NODES + 1;
    int* cursor = (int*)(wsf + o); o += N_NODES;
    int* col    = (int*)(wsf + o); o += E_TOT;

    hipMemsetAsync(wsf + zstart, 0, zbytes, stream);

    // ---- CSR (dst-sorted adjacency incl. self loops); reused by both layers ----
    deg_init <<<(N_NODES + 255) / 256, 256, 0, stream>>>(deg);
    deg_count<<<(N_EDGES + 255) / 256, 256, 0, stream>>>(edst, deg);
    scan_rowptr<<<1, 1024, 0, stream>>>(deg, rowptr, cursor);
    fill_csr <<<(E_TOT + 255) / 256, 256, 0, stream>>>(esrc, edst, cursor, col);

    // ---- Layer 1: BN1 (folded) -> GEMM+att -> softmax+aggregate (concat) ----
    bn_stats<F1><<<512, F1, 0, stream>>>(x, sums1, sumsq1);
    gemm_att<F1, false><<<N_NODES / ROWS, 256, 0, stream>>>(x, sums1, sumsq1, gamma1, beta1,
                                                            W1, att_src1, att_dst1,
                                                            hl, a_src1, a_dst1);
    node_aggr<false><<<N_NODES, 256, 0, stream>>>(rowptr, col, a_src1, a_dst1, hl, nullptr, acc1);

    // ---- Layer 2: BN2+ReLU (folded) -> GEMM+att -> softmax+aggregate (head mean + bias2) ----
    bn_stats<F2><<<512, F2, 0, stream>>>(acc1, sums2, sumsq2);
    gemm_att<F2, true><<<N_NODES / ROWS, 256, 0, stream>>>(acc1, sums2, sumsq2, gamma2, beta2,
                                                           W2, att_src2, att_dst2,
                                                           hl, a_src2, a_dst2);
    node_aggr<true><<<N_NODES, 256, 0, stream>>>(rowptr, col, a_src2, a_dst2, hl, bias2, out);
}

// Round 3
// 559.183 us; speedup vs baseline: 4.4739x; 1.4864x over previous
//
#include <hip/hip_runtime.h>

#define N_NODES 50000
#define N_EDGES 800000
#define E_TOT   (N_EDGES + N_NODES)   // self-loops appended
#define F1      128                   // IN_DIM
#define F2      256                   // HEADS*HIDDEN
#define EPS     1e-5f
#define SLOPE   0.2f
#define CAP     448                   // max in-LDS degree (deg ~ 1+Binomial, mean 17; tail << 448)
#define ROWS    20                    // rows per gemm block (50000 = 20*2500)
#define SCAN_B  256
#define N_BLKS  ((N_NODES + SCAN_B - 1) / SCAN_B)

__device__ __forceinline__ unsigned short bf16rne(float f) {
    unsigned u = __float_as_uint(f);
    u += 0x7fffu + ((u >> 16) & 1u);
    return (unsigned short)(u >> 16);
}
__device__ __forceinline__ float bf2f(unsigned short b) {
    return __uint_as_float((unsigned)b << 16);
}

// ---- column sums / sums-of-squares for training-mode BatchNorm ----
template<int C>
__global__ void bn_stats(const float* __restrict__ X,
                         float* __restrict__ sums, float* __restrict__ sumsq) {
    int t = threadIdx.x;            // blockDim.x == C
    float s = 0.f, q = 0.f;
    for (int r = blockIdx.x; r < N_NODES; r += gridDim.x) {
        float v = X[(size_t)r * C + t];
        s += v; q += v * v;
    }
    atomicAdd(&sums[t], s);
    atomicAdd(&sumsq[t], q);
}

// ---- fold BN into per-column scale/shift: y = x*scale + shift ----
__global__ void bn_coef(const float* __restrict__ sums, const float* __restrict__ sumsq,
                        const float* __restrict__ gamma, const float* __restrict__ beta,
                        float* __restrict__ scale, float* __restrict__ shift, int K) {
    int t = blockIdx.x * 64 + threadIdx.x;
    if (t < K) {
        const float invN = 1.f / (float)N_NODES;
        float m  = sums[t] * invN;
        float vv = sumsq[t] * invN - m * m;
        float sc = rsqrtf(vv + EPS) * gamma[t];
        scale[t] = sc;
        shift[t] = fmaf(-m, sc, beta[t]);
    }
}

// ---- CSR build ----
__global__ void deg_init(int* __restrict__ deg) {
    int i = blockIdx.x * 256 + threadIdx.x;
    if (i < N_NODES) deg[i] = 1;                 // self loop
}
__global__ void deg_count(const int* __restrict__ edst, int* __restrict__ deg) {
    int i = blockIdx.x * 256 + threadIdx.x;
    if (i < N_EDGES) atomicAdd(&deg[edst[i]], 1);
}
__global__ void scan_blocks(const int* __restrict__ deg, int* __restrict__ rowptr,
                            int* __restrict__ bsum) {
    __shared__ int sd[SCAN_B];
    int b = blockIdx.x, t = threadIdx.x;
    int i = b * SCAN_B + t;
    int v = (i < N_NODES) ? deg[i] : 0;
    sd[t] = v;
    __syncthreads();
    for (int off = 1; off < SCAN_B; off <<= 1) {
        int x = (t >= off) ? sd[t - off] : 0;
        __syncthreads();
        sd[t] += x;
        __syncthreads();
    }
    if (i < N_NODES) rowptr[i + 1] = sd[t];      // inclusive, pre-offset
    if (t == SCAN_B - 1) bsum[b] = sd[t];
}
__global__ void scan_totals(int* __restrict__ bsum) {   // single block
    __shared__ int sd[SCAN_B];
    int t = threadIdx.x;
    int v = (t < N_BLKS) ? bsum[t] : 0;
    sd[t] = v;
    __syncthreads();
    for (int off = 1; off < SCAN_B; off <<= 1) {
        int x = (t >= off) ? sd[t - off] : 0;
        __syncthreads();
        sd[t] += x;
        __syncthreads();
    }
    if (t < N_BLKS) bsum[t] = sd[t] - v;         // exclusive block offsets
}
__global__ void scan_apply(const int* __restrict__ deg, const int* __restrict__ bsum,
                           int* __restrict__ rowptr, int* __restrict__ cursor) {
    int i = blockIdx.x * SCAN_B + threadIdx.x;
    if (i < N_NODES) {
        int r = rowptr[i + 1] + bsum[blockIdx.x];
        rowptr[i + 1] = r;
        cursor[i] = r - deg[i];
        if (i == 0) rowptr[0] = 0;
    }
}
__global__ void fill_csr(const int* __restrict__ esrc, const int* __restrict__ edst,
                         int* __restrict__ cursor, int* __restrict__ col) {
    int i = blockIdx.x * 256 + threadIdx.x;
    if (i < N_EDGES) {
        int p = atomicAdd(&cursor[edst[i]], 1);
        col[p] = esrc[i];
    } else if (i < E_TOT) {
        int n = i - N_EDGES;                     // self loop
        int p = atomicAdd(&cursor[n], 1);
        col[p] = n;
    }
}

// ---- fused BN(+ReLU) -> GEMM (20 rows, 2 cols/thread) -> attention dots -> bf16 hl ----
template<int K, bool RELU>
__global__ __launch_bounds__(128)
void gemm_att(const float* __restrict__ X,
              const float* __restrict__ scale, const float* __restrict__ shift,
              const float* __restrict__ W,
              const float* __restrict__ att_s, const float* __restrict__ att_d,
              ushort2* __restrict__ hlb, float* __restrict__ a_src, float* __restrict__ a_dst) {
    int n0 = blockIdx.x * ROWS, t = threadIdx.x;
    __shared__ float sh[ROWS * K];
    const float4* X4  = (const float4*)(X + (size_t)n0 * K);
    const float4* sc4 = (const float4*)scale;
    const float4* sf4 = (const float4*)shift;
    float4* sh4 = (float4*)sh;
    for (int i = t; i < ROWS * K / 4; i += 128) {
        float4 xv = X4[i];
        int kq = i & (K / 4 - 1);
        float4 sc = sc4[kq], sf = sf4[kq];
        float4 y;
        y.x = fmaf(xv.x, sc.x, sf.x);
        y.y = fmaf(xv.y, sc.y, sf.y);
        y.z = fmaf(xv.z, sc.z, sf.z);
        y.w = fmaf(xv.w, sc.w, sf.w);
        if (RELU) {
            y.x = fmaxf(y.x, 0.f); y.y = fmaxf(y.y, 0.f);
            y.z = fmaxf(y.z, 0.f); y.w = fmaxf(y.w, 0.f);
        }
        sh4[i] = y;
    }
    __syncthreads();

    float acc0[ROWS], acc1[ROWS];
#pragma unroll
    for (int r = 0; r < ROWS; r++) { acc0[r] = 0.f; acc1[r] = 0.f; }

    const float2* wp = (const float2*)W + t;     // cols 2t, 2t+1 of row k at wp[k*128]
    for (int k = 0; k < K; k += 4) {
        float2 w0 = wp[(k + 0) * (F2 / 2)];
        float2 w1 = wp[(k + 1) * (F2 / 2)];
        float2 w2 = wp[(k + 2) * (F2 / 2)];
        float2 w3 = wp[(k + 3) * (F2 / 2)];
#pragma unroll
        for (int r = 0; r < ROWS; r++) {
            float4 xv = *(const float4*)&sh[r * K + k];
            acc0[r] = fmaf(xv.x, w0.x, acc0[r]); acc1[r] = fmaf(xv.x, w0.y, acc1[r]);
            acc0[r] = fmaf(xv.y, w1.x, acc0[r]); acc1[r] = fmaf(xv.y, w1.y, acc1[r]);
            acc0[r] = fmaf(xv.z, w2.x, acc0[r]); acc1[r] = fmaf(xv.z, w2.y, acc1[r]);
            acc0[r] = fmaf(xv.w, w3.x, acc0[r]); acc1[r] = fmaf(xv.w, w3.y, acc1[r]);
        }
    }

    float2 as = ((const float2*)att_s)[t];
    float2 ad = ((const float2*)att_d)[t];
    int h = t >> 5;                              // head of cols 2t,2t+1
#pragma unroll
    for (int r = 0; r < ROWS; r++) {
        ushort2 hv; hv.x = bf16rne(acc0[r]); hv.y = bf16rne(acc1[r]);
        hlb[(size_t)(n0 + r) * (F2 / 2) + t] = hv;
        float vs = acc0[r] * as.x + acc1[r] * as.y;
        float vd = acc0[r] * ad.x + acc1[r] * ad.y;
#pragma unroll
        for (int o = 1; o < 32; o <<= 1) { vs += __shfl_xor(vs, o); vd += __shfl_xor(vd, o); }
        if ((t & 31) == 0) { a_src[(n0 + r) * 4 + h] = vs; a_dst[(n0 + r) * 4 + h] = vd; }
    }
}

// ---- per-dst-node softmax + aggregation (no atomics, bf16 gather) ----
// exp(v)/sum exp(v) == exp(v-max)/sum exp(v-max) exactly; |v| is O(3), no overflow.
template<bool MEAN>
__global__ __launch_bounds__(128)
void node_aggr(const int* __restrict__ rowptr, const int* __restrict__ col,
               const float* __restrict__ a_src, const float* __restrict__ a_dst,
               const ushort2* __restrict__ hlb, const float* __restrict__ bias,
               float* __restrict__ out) {
    int n = blockIdx.x, t = threadIdx.x;
    int start = rowptr[n];
    int deg = rowptr[n + 1] - start;
    __shared__ float se[CAP * 4];
    __shared__ int   scol[CAP];
    __shared__ float wred[8];
    __shared__ float sdenom[4];
    int h4 = t & 3;
    float adn = a_dst[n * 4 + h4];
    float local = 0.f;
    bool fits = (deg <= CAP);
    if (fits) {
        for (int i = t; i < deg; i += 128) scol[i] = col[start + i];
        __syncthreads();
        for (int p = t; p < deg * 4; p += 128) {   // p&3 == t&3 == h4
            int i = p >> 2;
            float v = a_src[scol[i] * 4 + h4] + adn;
            v = v > 0.f ? v : SLOPE * v;
            float e = __expf(v);
            se[p] = e;
            local += e;
        }
    } else {
        for (int p = t; p < deg * 4; p += 128) {
            float v = a_src[col[start + (p >> 2)] * 4 + h4] + adn;
            v = v > 0.f ? v : SLOPE * v;
            local += __expf(v);
        }
    }
#pragma unroll
    for (int off = 4; off < 64; off <<= 1) local += __shfl_xor(local, off);
    if ((t & 63) < 4) wred[(t >> 6) * 4 + h4] = local;
    __syncthreads();
    if (t < 4) sdenom[t] = wred[t] + wred[t + 4];
    __syncthreads();

    int h = t >> 5;                               // head of cols 2t,2t+1
    float rden = 1.f / sdenom[h];
    float acc0 = 0.f, acc1 = 0.f;
    if (fits) {
#pragma unroll 4
        for (int i = 0; i < deg; i++) {
            float alpha = se[i * 4 + h] * rden;
            ushort2 hv = hlb[(size_t)scol[i] * (F2 / 2) + t];
            acc0 = fmaf(alpha, bf2f(hv.x), acc0);
            acc1 = fmaf(alpha, bf2f(hv.y), acc1);
        }
    } else {
        float adh = a_dst[n * 4 + h];
        for (int i = 0; i < deg; i++) {
            int s = col[start + i];
            float v = a_src[s * 4 + h] + adh;
            v = v > 0.f ? v : SLOPE * v;
            float alpha = __expf(v) * rden;
            ushort2 hv = hlb[(size_t)s * (F2 / 2) + t];
            acc0 = fmaf(alpha, bf2f(hv.x), acc0);
            acc1 = fmaf(alpha, bf2f(hv.y), acc1);
        }
    }
    if (MEAN) {
        __shared__ float sred[256];
        sred[2 * t] = acc0; sred[2 * t + 1] = acc1;
        __syncthreads();
        if (t < 64)
            out[(size_t)n * 64 + t] =
                0.25f * (sred[t] + sred[t + 64] + sred[t + 128] + sred[t + 192]) + bias[t];
    } else {
        float2 o; o.x = acc0; o.y = acc1;
        ((float2*)out)[(size_t)n * (F2 / 2) + t] = o;
    }
}

extern "C" void kernel_launch(void* const* d_in, const int* in_sizes, int n_in,
                              void* d_out, int out_size, void* d_ws, size_t ws_size,
                              hipStream_t stream) {
    const float* x        = (const float*)d_in[0];
    const int*   edge     = (const int*)  d_in[1];   // [2, E]: row0=src, row1=dst
    const float* gamma1   = (const float*)d_in[2];
    const float* beta1    = (const float*)d_in[3];
    const float* W1       = (const float*)d_in[4];
    const float* att_src1 = (const float*)d_in[5];
    const float* att_dst1 = (const float*)d_in[6];
    // d_in[7] = bias1: dead (absorbed by BatchNorm2's mean subtraction)
    const float* gamma2   = (const float*)d_in[8];
    const float* beta2    = (const float*)d_in[9];
    const float* W2       = (const float*)d_in[10];
    const float* att_src2 = (const float*)d_in[11];
    const float* att_dst2 = (const float*)d_in[12];
    const float* bias2    = (const float*)d_in[13];
    float* out = (float*)d_out;

    const int* esrc = edge;
    const int* edst = edge + N_EDGES;

    // ---- workspace layout (float offsets) ----
    float* wsf = (float*)d_ws;
    size_t o = 0;
    ushort2* hlb = (ushort2*)(wsf + o); o += (size_t)N_NODES * F2 / 2;  // bf16 hl, both layers
    float* acc1   = wsf + o; o += (size_t)N_NODES * F2;   // GAT1 output (fully overwritten)
    float* a_src1 = wsf + o; o += N_NODES * 4;
    float* a_dst1 = wsf + o; o += N_NODES * 4;
    float* a_src2 = wsf + o; o += N_NODES * 4;
    float* a_dst2 = wsf + o; o += N_NODES * 4;
    float* scale1 = wsf + o; o += F1;
    float* shift1 = wsf + o; o += F1;
    float* scale2 = wsf + o; o += F2;
    float* shift2 = wsf + o; o += F2;
    size_t zstart = o;                                     // ---- zeroed block ----
    float* sums1  = wsf + o; o += F1;
    float* sumsq1 = wsf + o; o += F1;
    float* sums2  = wsf + o; o += F2;
    float* sumsq2 = wsf + o; o += F2;
    size_t zbytes = (o - zstart) * sizeof(float);          // ---- end zeroed ----
    int* deg    = (int*)(wsf + o); o += N_NODES;
    int* rowptr = (int*)(wsf + o); o += N_NODES + 1;
    int* cursor = (int*)(wsf + o); o += N_NODES;
    int* bsum   = (int*)(wsf + o); o += SCAN_B;
    int* col    = (int*)(wsf + o); o += E_TOT;

    hipMemsetAsync(wsf + zstart, 0, zbytes, stream);

    // ---- CSR (dst-sorted adjacency incl. self loops); reused by both layers ----
    deg_init   <<<(N_NODES + 255) / 256, 256, 0, stream>>>(deg);
    deg_count  <<<(N_EDGES + 255) / 256, 256, 0, stream>>>(edst, deg);
    scan_blocks<<<N_BLKS, SCAN_B, 0, stream>>>(deg, rowptr, bsum);
    scan_totals<<<1, SCAN_B, 0, stream>>>(bsum);
    scan_apply <<<N_BLKS, SCAN_B, 0, stream>>>(deg, bsum, rowptr, cursor);
    fill_csr   <<<(E_TOT + 255) / 256, 256, 0, stream>>>(esrc, edst, cursor, col);

    // ---- Layer 1: BN1 (folded) -> GEMM+att -> softmax+aggregate (concat) ----
    bn_stats<F1><<<512, F1, 0, stream>>>(x, sums1, sumsq1);
    bn_coef<<<(F1 + 63) / 64, 64, 0, stream>>>(sums1, sumsq1, gamma1, beta1, scale1, shift1, F1);
    gemm_att<F1, false><<<N_NODES / ROWS, 128, 0, stream>>>(x, scale1, shift1,
                                                            W1, att_src1, att_dst1,
                                                            hlb, a_src1, a_dst1);
    node_aggr<false><<<N_NODES, 128, 0, stream>>>(rowptr, col, a_src1, a_dst1, hlb, nullptr, acc1);

    // ---- Layer 2: BN2+ReLU (folded) -> GEMM+att -> softmax+aggregate (head mean + bias2) ----
    bn_stats<F2><<<512, F2, 0, stream>>>(acc1, sums2, sumsq2);
    bn_coef<<<(F2 + 63) / 64, 64, 0, stream>>>(sums2, sumsq2, gamma2, beta2, scale2, shift2, F2);
    gemm_att<F2, true><<<N_NODES / ROWS, 128, 0, stream>>>(acc1, scale2, shift2,
                                                           W2, att_src2, att_dst2,
                                                           hlb, a_src2, a_dst2);
    node_aggr<true><<<N_NODES, 128, 0, stream>>>(rowptr, col, a_src2, a_dst2, hlb, bias2, out);
}

// Round 4
// 499.900 us; speedup vs baseline: 5.0044x; 1.1186x over previous
//
#include <hip/hip_runtime.h>

#define N_NODES 50000
#define N_EDGES 800000
#define E_TOT   (N_EDGES + N_NODES)   // self-loops appended
#define F1      128                   // IN_DIM
#define F2      256                   // HEADS*HIDDEN
#define EPS     1e-5f
#define SLOPE   0.2f
#define CAP     448                   // max in-LDS degree (deg ~ 1+Binomial(mean 16); tail << 448)
#define SCAN_B  256
#define N_BLKS  ((N_NODES + SCAN_B - 1) / SCAN_B)

typedef __bf16 bf16x8 __attribute__((ext_vector_type(8)));
typedef float  f32x4  __attribute__((ext_vector_type(4)));

__device__ __forceinline__ float bf2f(unsigned short b) {
    return __uint_as_float((unsigned)b << 16);
}

// ---- column sums / sums-of-squares for training-mode BatchNorm ----
template<int C>
__global__ void bn_stats(const float* __restrict__ X,
                         float* __restrict__ sums, float* __restrict__ sumsq) {
    int t = threadIdx.x;            // blockDim.x == C
    float s = 0.f, q = 0.f;
    for (int r = blockIdx.x; r < N_NODES; r += gridDim.x) {
        float v = X[(size_t)r * C + t];
        s += v; q += v * v;
    }
    atomicAdd(&sums[t], s);
    atomicAdd(&sumsq[t], q);
}

// ---- fold BN into per-column scale/shift: y = x*scale + shift ----
__global__ void bn_coef(const float* __restrict__ sums, const float* __restrict__ sumsq,
                        const float* __restrict__ gamma, const float* __restrict__ beta,
                        float* __restrict__ scale, float* __restrict__ shift, int K) {
    int t = blockIdx.x * 64 + threadIdx.x;
    if (t < K) {
        const float invN = 1.f / (float)N_NODES;
        float m  = sums[t] * invN;
        float vv = sumsq[t] * invN - m * m;
        float sc = rsqrtf(vv + EPS) * gamma[t];
        scale[t] = sc;
        shift[t] = fmaf(-m, sc, beta[t]);
    }
}

// ---- CSR build ----
__global__ void deg_init(int* __restrict__ deg) {
    int i = blockIdx.x * 256 + threadIdx.x;
    if (i < N_NODES) deg[i] = 1;                 // self loop
}
__global__ void deg_count(const int* __restrict__ edst, int* __restrict__ deg) {
    int i = blockIdx.x * 256 + threadIdx.x;
    if (i < N_EDGES) atomicAdd(&deg[edst[i]], 1);
}
__global__ void scan_blocks(const int* __restrict__ deg, int* __restrict__ rowptr,
                            int* __restrict__ bsum) {
    __shared__ int sd[SCAN_B];
    int b = blockIdx.x, t = threadIdx.x;
    int i = b * SCAN_B + t;
    int v = (i < N_NODES) ? deg[i] : 0;
    sd[t] = v;
    __syncthreads();
    for (int off = 1; off < SCAN_B; off <<= 1) {
        int x = (t >= off) ? sd[t - off] : 0;
        __syncthreads();
        sd[t] += x;
        __syncthreads();
    }
    if (i < N_NODES) rowptr[i + 1] = sd[t];      // inclusive, pre-offset
    if (t == SCAN_B - 1) bsum[b] = sd[t];
}
__global__ void scan_totals(int* __restrict__ bsum) {   // single block
    __shared__ int sd[SCAN_B];
    int t = threadIdx.x;
    int v = (t < N_BLKS) ? bsum[t] : 0;
    sd[t] = v;
    __syncthreads();
    for (int off = 1; off < SCAN_B; off <<= 1) {
        int x = (t >= off) ? sd[t - off] : 0;
        __syncthreads();
        sd[t] += x;
        __syncthreads();
    }
    if (t < N_BLKS) bsum[t] = sd[t] - v;         // exclusive block offsets
}
__global__ void scan_apply(const int* __restrict__ deg, const int* __restrict__ bsum,
                           int* __restrict__ rowptr, int* __restrict__ cursor) {
    int i = blockIdx.x * SCAN_B + threadIdx.x;
    if (i < N_NODES) {
        int r = rowptr[i + 1] + bsum[blockIdx.x];
        rowptr[i + 1] = r;
        cursor[i] = r - deg[i];
        if (i == 0) rowptr[0] = 0;
    }
}
__global__ void fill_csr(const int* __restrict__ esrc, const int* __restrict__ edst,
                         int* __restrict__ cursor, int* __restrict__ col) {
    int i = blockIdx.x * 256 + threadIdx.x;
    if (i < N_EDGES) {
        int p = atomicAdd(&cursor[edst[i]], 1);
        col[p] = esrc[i];
    } else if (i < E_TOT) {
        int n = i - N_EDGES;                     // self loop
        int p = atomicAdd(&cursor[n], 1);
        col[p] = n;
    }
}

// ---- W [K][256] fp32 -> bf16 B-fragments in MFMA order ----
// B-frag (16x16x32): lane l holds B[k=ks*32+(l>>4)*8+j][col=nt*16+(l&15)], j=0..7.
// Stored so gemm reads Wf + ((ks*16+nt)*64+lane)*8 as one contiguous 16B/lane load.
template<int K>
__global__ void prep_w(const float* __restrict__ W, __bf16* __restrict__ Wf) {
    int tid = blockIdx.x * 256 + threadIdx.x;    // (K/32)*16*64 total
    if (tid >= (K / 32) * 16 * 64) return;
    int lane = tid & 63;
    int nt = (tid >> 6) & 15;
    int ks = tid >> 10;
    int q = lane >> 4, c = lane & 15;
#pragma unroll
    for (int j = 0; j < 8; j++)
        Wf[(size_t)tid * 8 + j] = (__bf16)W[(size_t)(ks * 32 + q * 8 + j) * F2 + nt * 16 + c];
}

// ---- fused BN(+ReLU) -> MFMA GEMM -> bf16 hl ----
// One wave = 32 rows x 256 cols. A-frags straight from global (no LDS, no barriers).
template<int K, bool RELU>
__global__ __launch_bounds__(256)
void gemm_mfma(const float* __restrict__ X,
               const float* __restrict__ scale, const float* __restrict__ shift,
               const __bf16* __restrict__ Wf, __bf16* __restrict__ hlb) {
    int t = threadIdx.x;
    int wave = t >> 6, lane = t & 63;
    int q = lane >> 4, c = lane & 15;
    int mrow = (blockIdx.x * 4 + wave) * 32;
    int row0 = mrow + c, row1 = mrow + 16 + c;
    int r0 = row0 < N_NODES ? row0 : N_NODES - 1;   // clamp loads; stores guarded
    int r1 = row1 < N_NODES ? row1 : N_NODES - 1;

    f32x4 acc[2][16];
#pragma unroll
    for (int m = 0; m < 2; m++)
#pragma unroll
        for (int nt = 0; nt < 16; nt++) acc[m][nt] = (f32x4){0.f, 0.f, 0.f, 0.f};

    for (int ks = 0; ks < K / 32; ks++) {
        int kb = ks * 32 + q * 8;
        float4 sc0 = *(const float4*)(scale + kb);
        float4 sc1 = *(const float4*)(scale + kb + 4);
        float4 sf0 = *(const float4*)(shift + kb);
        float4 sf1 = *(const float4*)(shift + kb + 4);
        bf16x8 afr[2];
#pragma unroll
        for (int m = 0; m < 2; m++) {
            const float* xp = X + (size_t)(m ? r1 : r0) * K + kb;
            float4 x0 = *(const float4*)xp;
            float4 x1 = *(const float4*)(xp + 4);
            float y0 = fmaf(x0.x, sc0.x, sf0.x);
            float y1 = fmaf(x0.y, sc0.y, sf0.y);
            float y2 = fmaf(x0.z, sc0.z, sf0.z);
            float y3 = fmaf(x0.w, sc0.w, sf0.w);
            float y4 = fmaf(x1.x, sc1.x, sf1.x);
            float y5 = fmaf(x1.y, sc1.y, sf1.y);
            float y6 = fmaf(x1.z, sc1.z, sf1.z);
            float y7 = fmaf(x1.w, sc1.w, sf1.w);
            if (RELU) {
                y0 = fmaxf(y0, 0.f); y1 = fmaxf(y1, 0.f);
                y2 = fmaxf(y2, 0.f); y3 = fmaxf(y3, 0.f);
                y4 = fmaxf(y4, 0.f); y5 = fmaxf(y5, 0.f);
                y6 = fmaxf(y6, 0.f); y7 = fmaxf(y7, 0.f);
            }
            bf16x8 a;
            a[0] = (__bf16)y0; a[1] = (__bf16)y1; a[2] = (__bf16)y2; a[3] = (__bf16)y3;
            a[4] = (__bf16)y4; a[5] = (__bf16)y5; a[6] = (__bf16)y6; a[7] = (__bf16)y7;
            afr[m] = a;
        }
#pragma unroll
        for (int nt = 0; nt < 16; nt++) {
            bf16x8 b = *(const bf16x8*)(Wf + ((size_t)(ks * 16 + nt) * 64 + lane) * 8);
            acc[0][nt] = __builtin_amdgcn_mfma_f32_16x16x32_bf16(afr[0], b, acc[0][nt], 0, 0, 0);
            acc[1][nt] = __builtin_amdgcn_mfma_f32_16x16x32_bf16(afr[1], b, acc[1][nt], 0, 0, 0);
        }
    }
    // C/D layout: col = nt*16 + (lane&15), row = mtile*16 + (lane>>4)*4 + reg
#pragma unroll
    for (int m = 0; m < 2; m++) {
        int rowb = mrow + m * 16 + q * 4;
#pragma unroll
        for (int r = 0; r < 4; r++) {
            int row = rowb + r;
            if (row < N_NODES) {
#pragma unroll
                for (int nt = 0; nt < 16; nt++)
                    hlb[(size_t)row * F2 + nt * 16 + c] = (__bf16)acc[m][nt][r];
            }
        }
    }
}

// ---- per-node attention dots: a_src/a_dst[n,h] = sum_c hl[n,h*64+c]*att[h*64+c] ----
__global__ __launch_bounds__(256)
void att_dots(const __bf16* __restrict__ hlb,
              const float* __restrict__ att_s, const float* __restrict__ att_d,
              float* __restrict__ a_src, float* __restrict__ a_dst) {
    int t = threadIdx.x;
    int wave = t >> 6, lane = t & 63;
    int n = blockIdx.x * 4 + wave;               // 50000 = 4*12500
    ushort4 hv = ((const ushort4*)(hlb + (size_t)n * F2))[lane];
    float4 as = ((const float4*)att_s)[lane];
    float4 ad = ((const float4*)att_d)[lane];
    float v0 = bf2f(hv.x), v1 = bf2f(hv.y), v2 = bf2f(hv.z), v3 = bf2f(hv.w);
    float vs = v0 * as.x + v1 * as.y + v2 * as.z + v3 * as.w;
    float vd = v0 * ad.x + v1 * ad.y + v2 * ad.z + v3 * ad.w;
#pragma unroll
    for (int off = 1; off < 16; off <<= 1) { vs += __shfl_xor(vs, off); vd += __shfl_xor(vd, off); }
    if ((lane & 15) == 0) {
        int h = lane >> 4;
        a_src[n * 4 + h] = vs;
        a_dst[n * 4 + h] = vd;
    }
}

// ---- per-dst-node softmax + aggregation (no atomics, bf16 gather) ----
// exp(v)/sum exp(v) == exp(v-max)/sum exp(v-max) exactly; |v| is O(3), no overflow.
template<bool MEAN>
__global__ __launch_bounds__(128)
void node_aggr(const int* __restrict__ rowptr, const int* __restrict__ col,
               const float* __restrict__ a_src, const float* __restrict__ a_dst,
               const ushort2* __restrict__ hlb, const float* __restrict__ bias,
               float* __restrict__ out) {
    int n = blockIdx.x, t = threadIdx.x;
    int start = rowptr[n];
    int deg = rowptr[n + 1] - start;
    __shared__ float se[CAP * 4];
    __shared__ int   scol[CAP];
    __shared__ float wred[8];
    __shared__ float sdenom[4];
    int h4 = t & 3;
    float adn = a_dst[n * 4 + h4];
    float local = 0.f;
    bool fits = (deg <= CAP);
    if (fits) {
        for (int i = t; i < deg; i += 128) scol[i] = col[start + i];
        __syncthreads();
        for (int p = t; p < deg * 4; p += 128) {   // p&3 == t&3 == h4
            int i = p >> 2;
            float v = a_src[scol[i] * 4 + h4] + adn;
            v = v > 0.f ? v : SLOPE * v;
            float e = __expf(v);
            se[p] = e;
            local += e;
        }
    } else {
        for (int p = t; p < deg * 4; p += 128) {
            float v = a_src[col[start + (p >> 2)] * 4 + h4] + adn;
            v = v > 0.f ? v : SLOPE * v;
            local += __expf(v);
        }
    }
#pragma unroll
    for (int off = 4; off < 64; off <<= 1) local += __shfl_xor(local, off);
    if ((t & 63) < 4) wred[(t >> 6) * 4 + h4] = local;
    __syncthreads();
    if (t < 4) sdenom[t] = wred[t] + wred[t + 4];
    __syncthreads();

    int h = t >> 5;                               // head of cols 2t,2t+1
    float rden = 1.f / sdenom[h];
    float acc0 = 0.f, acc1 = 0.f;
    if (fits) {
#pragma unroll 4
        for (int i = 0; i < deg; i++) {
            float alpha = se[i * 4 + h] * rden;
            ushort2 hv = hlb[(size_t)scol[i] * (F2 / 2) + t];
            acc0 = fmaf(alpha, bf2f(hv.x), acc0);
            acc1 = fmaf(alpha, bf2f(hv.y), acc1);
        }
    } else {
        float adh = a_dst[n * 4 + h];
        for (int i = 0; i < deg; i++) {
            int s = col[start + i];
            float v = a_src[s * 4 + h] + adh;
            v = v > 0.f ? v : SLOPE * v;
            float alpha = __expf(v) * rden;
            ushort2 hv = hlb[(size_t)s * (F2 / 2) + t];
            acc0 = fmaf(alpha, bf2f(hv.x), acc0);
            acc1 = fmaf(alpha, bf2f(hv.y), acc1);
        }
    }
    if (MEAN) {
        __shared__ float sred[256];
        sred[2 * t] = acc0; sred[2 * t + 1] = acc1;
        __syncthreads();
        if (t < 64)
            out[(size_t)n * 64 + t] =
                0.25f * (sred[t] + sred[t + 64] + sred[t + 128] + sred[t + 192]) + bias[t];
    } else {
        float2 o; o.x = acc0; o.y = acc1;
        ((float2*)out)[(size_t)n * (F2 / 2) + t] = o;
    }
}

extern "C" void kernel_launch(void* const* d_in, const int* in_sizes, int n_in,
                              void* d_out, int out_size, void* d_ws, size_t ws_size,
                              hipStream_t stream) {
    const float* x        = (const float*)d_in[0];
    const int*   edge     = (const int*)  d_in[1];   // [2, E]: row0=src, row1=dst
    const float* gamma1   = (const float*)d_in[2];
    const float* beta1    = (const float*)d_in[3];
    const float* W1       = (const float*)d_in[4];
    const float* att_src1 = (const float*)d_in[5];
    const float* att_dst1 = (const float*)d_in[6];
    // d_in[7] = bias1: dead (absorbed by BatchNorm2's mean subtraction)
    const float* gamma2   = (const float*)d_in[8];
    const float* beta2    = (const float*)d_in[9];
    const float* W2       = (const float*)d_in[10];
    const float* att_src2 = (const float*)d_in[11];
    const float* att_dst2 = (const float*)d_in[12];
    const float* bias2    = (const float*)d_in[13];
    float* out = (float*)d_out;

    const int* esrc = edge;
    const int* edst = edge + N_EDGES;

    // ---- workspace layout (float offsets) ----
    float* wsf = (float*)d_ws;
    size_t o = 0;
    __bf16* hlb = (__bf16*)(wsf + o); o += (size_t)N_NODES * F2 / 2;  // bf16 hl, both layers
    float* acc1   = wsf + o; o += (size_t)N_NODES * F2;   // GAT1 output (fully overwritten)
    __bf16* Wf1 = (__bf16*)(wsf + o); o += (size_t)F1 * F2 / 2;
    __bf16* Wf2 = (__bf16*)(wsf + o); o += (size_t)F2 * F2 / 2;
    float* a_src1 = wsf + o; o += N_NODES * 4;
    float* a_dst1 = wsf + o; o += N_NODES * 4;
    float* a_src2 = wsf + o; o += N_NODES * 4;
    float* a_dst2 = wsf + o; o += N_NODES * 4;
    float* scale1 = wsf + o; o += F1;
    float* shift1 = wsf + o; o += F1;
    float* scale2 = wsf + o; o += F2;
    float* shift2 = wsf + o; o += F2;
    size_t zstart = o;                                     // ---- zeroed block ----
    float* sums1  = wsf + o; o += F1;
    float* sumsq1 = wsf + o; o += F1;
    float* sums2  = wsf + o; o += F2;
    float* sumsq2 = wsf + o; o += F2;
    size_t zbytes = (o - zstart) * sizeof(float);          // ---- end zeroed ----
    int* deg    = (int*)(wsf + o); o += N_NODES;
    int* rowptr = (int*)(wsf + o); o += N_NODES + 1;
    int* cursor = (int*)(wsf + o); o += N_NODES;
    int* bsum   = (int*)(wsf + o); o += SCAN_B;
    int* col    = (int*)(wsf + o); o += E_TOT;

    hipMemsetAsync(wsf + zstart, 0, zbytes, stream);

    // ---- CSR (dst-sorted adjacency incl. self loops); reused by both layers ----
    deg_init   <<<(N_NODES + 255) / 256, 256, 0, stream>>>(deg);
    deg_count  <<<(N_EDGES + 255) / 256, 256, 0, stream>>>(edst, deg);
    scan_blocks<<<N_BLKS, SCAN_B, 0, stream>>>(deg, rowptr, bsum);
    scan_totals<<<1, SCAN_B, 0, stream>>>(bsum);
    scan_apply <<<N_BLKS, SCAN_B, 0, stream>>>(deg, bsum, rowptr, cursor);
    fill_csr   <<<(E_TOT + 255) / 256, 256, 0, stream>>>(esrc, edst, cursor, col);

    // ---- W -> bf16 MFMA fragment order (once each) ----
    prep_w<F1><<<(F1 / 32) * 16 * 64 / 256, 256, 0, stream>>>(W1, Wf1);
    prep_w<F2><<<(F2 / 32) * 16 * 64 / 256, 256, 0, stream>>>(W2, Wf2);

    const int gemm_grid = (N_NODES + 127) / 128;           // 4 waves x 32 rows per block

    // ---- Layer 1: BN1 (folded) -> MFMA GEMM -> att dots -> softmax+aggregate (concat) ----
    bn_stats<F1><<<512, F1, 0, stream>>>(x, sums1, sumsq1);
    bn_coef<<<(F1 + 63) / 64, 64, 0, stream>>>(sums1, sumsq1, gamma1, beta1, scale1, shift1, F1);
    gemm_mfma<F1, false><<<gemm_grid, 256, 0, stream>>>(x, scale1, shift1, Wf1, hlb);
    att_dots<<<N_NODES / 4, 256, 0, stream>>>(hlb, att_src1, att_dst1, a_src1, a_dst1);
    node_aggr<false><<<N_NODES, 128, 0, stream>>>(rowptr, col, a_src1, a_dst1,
                                                  (const ushort2*)hlb, nullptr, acc1);

    // ---- Layer 2: BN2+ReLU (folded) -> MFMA GEMM -> att dots -> aggregate (head mean + bias2) ----
    bn_stats<F2><<<512, F2, 0, stream>>>(acc1, sums2, sumsq2);
    bn_coef<<<(F2 + 63) / 64, 64, 0, stream>>>(sums2, sumsq2, gamma2, beta2, scale2, shift2, F2);
    gemm_mfma<F2, true><<<gemm_grid, 256, 0, stream>>>(acc1, scale2, shift2, Wf2, hlb);
    att_dots<<<N_NODES / 4, 256, 0, stream>>>(hlb, att_src2, att_dst2, a_src2, a_dst2);
    node_aggr<true><<<N_NODES, 128, 0, stream>>>(rowptr, col, a_src2, a_dst2,
                                                 (const ushort2*)hlb, bias2, out);
}